// Round 8
// baseline (2824.228 us; speedup 1.0000x reference)
//
#include <hip/hip_runtime.h>
#include <stdint.h>

typedef _Float16 f16;
typedef _Float16 f16x8 __attribute__((ext_vector_type(8)));
typedef float f32x4 __attribute__((ext_vector_type(4)));

#define INF_F __builtin_inff()
#define KM 24   // merge candidate margin

__device__ __forceinline__ bool lexLess(float s1, int n1, float s2, int n2) {
    return (s1 < s2) || (s1 == s2 && n1 < n2);
}

#define GLOAD_LDS16(gsrc, ldst)                                                  \
    __builtin_amdgcn_global_load_lds(                                            \
        (const __attribute__((address_space(1))) uint32_t*)(gsrc),               \
        (__attribute__((address_space(3))) uint32_t*)(ldst), 16, 0, 0)

#define FENCE() asm volatile("" ::: "memory")
#define WAITV8() asm volatile("s_waitcnt vmcnt(8)" ::: "memory")
#define WAITL0() asm volatile("s_waitcnt lgkmcnt(0)" ::: "memory")
#define BAR() __builtin_amdgcn_s_barrier()

// ---------------------------------------------------------------------------
// Kernel 0: pack brep [64,512] f32 -> f16 MFMA A-fragments, coalesced layout:
// xfrag[(ks*4+ms)*64 + lane] = uint4 of A[m=ms*16+(lane&15)]
// [k = ks*32 + (lane>>4)*8 + j], j=0..7.
// ---------------------------------------------------------------------------
__global__ __launch_bounds__(256) void prepack_kernel(
    const float* __restrict__ brep, uint4* __restrict__ xfrag)
{
    const int e = blockIdx.x * 256 + threadIdx.x;   // 0..4095
    if (e >= 4096) return;
    const int lane = e & 63;
    const int ms = (e >> 6) & 3;
    const int ks = e >> 8;
    const int m = ms * 16 + (lane & 15);
    const int k = ks * 32 + (lane >> 4) * 8;
    const float* src = brep + m * 512 + k;
    unsigned short hb[8];
    #pragma unroll
    for (int j = 0; j < 8; j++) {
        f16 v = (f16)src[j];
        hb[j] = __builtin_bit_cast(unsigned short, v);
    }
    uint4 o;
    o.x = (unsigned)hb[0] | ((unsigned)hb[1] << 16);
    o.y = (unsigned)hb[2] | ((unsigned)hb[3] << 16);
    o.z = (unsigned)hb[4] | ((unsigned)hb[5] << 16);
    o.w = (unsigned)hb[6] | ((unsigned)hb[7] << 16);
    xfrag[e] = o;
}

// ---------------------------------------------------------------------------
// Kernel 1: LDS-staged streaming scores + per-block top-16 per batch row.
// 256 threads / 4 waves, 64-row tiles, K chunked by 64 floats (16KB chunks),
// triple-buffered via global_load_lds (contiguous wave writes; inverse-XOR-
// swizzled per-lane SOURCE so the swizzled ds_read is conflict-free).
// Counted vmcnt(8) + raw s_barrier: 2 chunks always in HBM flight.
// A-fragments live in LDS (lgkm queue, separate from the y vmcnt stream).
// Scan: SINGLE shared top-16 list per row; full state (threshold+count) in
// LDS; the scanning wave rotates per tile and resumes the shared state.
// ---------------------------------------------------------------------------
__global__ __launch_bounds__(256) void dist_topk_kernel(
    const float* __restrict__ reps, const uint4* __restrict__ xfrag,
    float* __restrict__ cs, int* __restrict__ ci,
    int N, int tilesBase, int tilesRem)
{
    __shared__ uint4 afr[4096];                       // 64 KB A-fragments
    __shared__ __align__(16) char ybuf[3][16384];     // 48 KB y triple-buffer
    __shared__ __align__(16) float slds[64][68];      // 17.4 KB scores
    __shared__ float topd[16][64];                    // 4 KB
    __shared__ int   topi[16][64];                    // 4 KB
    __shared__ float thrS[64];
    __shared__ int   thrnS[64];
    __shared__ int   cntS[64];

    const int tid = threadIdx.x;
    const int w = tid >> 6, lane = tid & 63;
    const int li = lane & 15, q = lane >> 4;
    const int xr = li & 7;
    const int b = blockIdx.x;
    const int t0 = b * tilesBase + min(b, tilesRem);
    const int tcount = tilesBase + (b < tilesRem ? 1 : 0);
    const int lastChunk = tcount * 8 - 1;

    // ---- one-time: fill A-fragment LDS (coalesced linear) ----
    #pragma unroll
    for (int i = 0; i < 16; i++) {
        const int e = i * 256 + w * 64;               // wave-uniform base
        GLOAD_LDS16(xfrag + e + lane, (char*)afr + (size_t)e * 16);
    }

    if (tid < 64) { thrS[tid] = INF_F; thrnS[tid] = 0x7fffffff; cntS[tid] = 0; }
    __syncthreads();

    // stage chunk gc: 64 rows x 64 floats (256B/row), linear LDS dest,
    // inverse-swizzled global source: LDS slot (row,p) <- global piece p^(row&7)
    auto stage = [&](int gc) {
        const int tI = gc >> 3, cc = gc & 7;
        const int n0s = (t0 + tI) * 64;
        const int kc = cc * 64;
        char* dstBase = ybuf[gc % 3];
        #pragma unroll
        for (int i = 0; i < 4; i++) {
            const int s = i * 256 + tid;
            const int row = s >> 4, p = s & 15;
            int grow = n0s + row; if (grow >= N) grow = N - 1;
            const float* src = reps + (size_t)grow * 512 + kc + ((p ^ (row & 7)) << 2);
            GLOAD_LDS16(src, dstBase + (i * 256 + w * 64) * 16);
        }
    };

    stage(0);
    stage(min(1, lastChunk));

    for (int ti = 0; ti < tcount; ti++) {
        const int n0 = (t0 + ti) * 64;
        const int row = n0 + 16 * w + li;

        f32x4 acc0 = {0.f,0.f,0.f,0.f}, acc1 = {0.f,0.f,0.f,0.f};
        f32x4 acc2 = {0.f,0.f,0.f,0.f}, acc3 = {0.f,0.f,0.f,0.f};
        float ynacc = 0.f;

        for (int cc = 0; cc < 8; cc++) {
            const int g = ti * 8 + cc;
            FENCE(); BAR(); FENCE();        // B1: all waves done reading buf[(g+2)%3]
            stage(min(g + 2, lastChunk));   // clamped restage is idempotent
            WAITV8();                       // chunk g landed; g+1,g+2 in flight
            BAR(); FENCE();                 // B2: all waves' chunk-g writes visible
            __builtin_amdgcn_sched_barrier(0);

            const char* yb = &ybuf[g % 3][(16 * w + li) * 256];
            #pragma unroll
            for (int ksl = 0; ksl < 2; ksl++) {
                const int ks = cc * 2 + ksl;
                const int pf = ksl * 8 + q * 2;
                const float4 y0 = *(const float4*)(yb + ((pf    ) ^ xr) * 16);
                const float4 y1 = *(const float4*)(yb + ((pf + 1) ^ xr) * 16);
                ynacc = fmaf(y0.x, y0.x, fmaf(y0.y, y0.y, fmaf(y0.z, y0.z, fmaf(y0.w, y0.w, ynacc))));
                ynacc = fmaf(y1.x, y1.x, fmaf(y1.y, y1.y, fmaf(y1.z, y1.z, fmaf(y1.w, y1.w, ynacc))));
                const auto p0 = __builtin_amdgcn_cvt_pkrtz(y0.x, y0.y);
                const auto p1 = __builtin_amdgcn_cvt_pkrtz(y0.z, y0.w);
                const auto p2 = __builtin_amdgcn_cvt_pkrtz(y1.x, y1.y);
                const auto p3 = __builtin_amdgcn_cvt_pkrtz(y1.z, y1.w);
                uint4 bu;
                bu.x = __builtin_bit_cast(unsigned, p0);
                bu.y = __builtin_bit_cast(unsigned, p1);
                bu.z = __builtin_bit_cast(unsigned, p2);
                bu.w = __builtin_bit_cast(unsigned, p3);
                const f16x8 bf = __builtin_bit_cast(f16x8, bu);
                const uint4 a0u = afr[(ks * 4 + 0) * 64 + lane];
                const uint4 a1u = afr[(ks * 4 + 1) * 64 + lane];
                const uint4 a2u = afr[(ks * 4 + 2) * 64 + lane];
                const uint4 a3u = afr[(ks * 4 + 3) * 64 + lane];
                acc0 = __builtin_amdgcn_mfma_f32_16x16x32_f16(__builtin_bit_cast(f16x8, a0u), bf, acc0, 0, 0, 0);
                acc1 = __builtin_amdgcn_mfma_f32_16x16x32_f16(__builtin_bit_cast(f16x8, a1u), bf, acc1, 0, 0, 0);
                acc2 = __builtin_amdgcn_mfma_f32_16x16x32_f16(__builtin_bit_cast(f16x8, a2u), bf, acc2, 0, 0, 0);
                acc3 = __builtin_amdgcn_mfma_f32_16x16x32_f16(__builtin_bit_cast(f16x8, a3u), bf, acc3, 0, 0, 0);
            }
        }

        // full ||y||^2 for this lane's row (reduce over the 4 k-quarters)
        ynacc += __shfl_xor(ynacc, 16);
        ynacc += __shfl_xor(ynacc, 32);
        const float yn = (row < N) ? ynacc : INF_F;   // pad rows -> +inf s

        // D layout: col n = lane&15, row m(within 16) = 4*q + reg
        {
            const int nl = 16 * w + li;
            float4 sv;
            sv.x = fmaf(-2.f, acc0[0], yn); sv.y = fmaf(-2.f, acc0[1], yn);
            sv.z = fmaf(-2.f, acc0[2], yn); sv.w = fmaf(-2.f, acc0[3], yn);
            *(float4*)(&slds[nl][0  + 4 * q]) = sv;
            sv.x = fmaf(-2.f, acc1[0], yn); sv.y = fmaf(-2.f, acc1[1], yn);
            sv.z = fmaf(-2.f, acc1[2], yn); sv.w = fmaf(-2.f, acc1[3], yn);
            *(float4*)(&slds[nl][16 + 4 * q]) = sv;
            sv.x = fmaf(-2.f, acc2[0], yn); sv.y = fmaf(-2.f, acc2[1], yn);
            sv.z = fmaf(-2.f, acc2[2], yn); sv.w = fmaf(-2.f, acc2[3], yn);
            *(float4*)(&slds[nl][32 + 4 * q]) = sv;
            sv.x = fmaf(-2.f, acc3[0], yn); sv.y = fmaf(-2.f, acc3[1], yn);
            sv.z = fmaf(-2.f, acc3[2], yn); sv.w = fmaf(-2.f, acc3[3], yn);
            *(float4*)(&slds[nl][48 + 4 * q]) = sv;
        }
        WAITL0();
        BAR(); FENCE();                               // s-matrix + prior scan state visible

        // per-row top-16 scan; scanning wave rotates per tile; the FULL scan
        // state (list + threshold + count) lives in LDS and is handed across
        // waves through the barriers above.
        if (w == (ti & 3)) {
            const int r = lane;
            float thr = thrS[r]; int thrn = thrnS[r]; int cnt = cntS[r];
            #pragma unroll 4
            for (int j = 0; j < 64; j++) {
                const float s = slds[j][r];
                const int n = n0 + j;
                if (lexLess(s, n, thr, thrn)) {
                    if (cnt < 16) {
                        topd[cnt][r] = s; topi[cnt][r] = n; cnt++;
                        if (cnt == 16) {
                            float tv = topd[0][r]; int tn = topi[0][r];
                            #pragma unroll
                            for (int u = 1; u < 16; u++) {
                                float v = topd[u][r]; int nn = topi[u][r];
                                if (!lexLess(v, nn, tv, tn)) { tv = v; tn = nn; }
                            }
                            thr = tv; thrn = tn;
                        }
                    } else {
                        #pragma unroll
                        for (int u = 0; u < 16; u++)
                            if (topd[u][r] == thr && topi[u][r] == thrn) {
                                topd[u][r] = s; topi[u][r] = n; break;
                            }
                        float tv = topd[0][r]; int tn = topi[0][r];
                        #pragma unroll
                        for (int u = 1; u < 16; u++) {
                            float v = topd[u][r]; int nn = topi[u][r];
                            if (!lexLess(v, nn, tv, tn)) { tv = v; tn = nn; }
                        }
                        thr = tv; thrn = tn;
                    }
                }
            }
            thrS[r] = thr; thrnS[r] = thrn; cntS[r] = cnt;
        }
    }

    __syncthreads();
    if (tid < 64) {
        const int c = cntS[tid];
        const size_t base = ((size_t)b * 64 + tid) * 16;
        for (int j = 0; j < 16; j++) {
            cs[base + j] = (j < c) ? topd[j][tid] : INF_F;
            ci[base + j] = (j < c) ? topi[j][tid] : 0x7fffffff;
        }
    }
}

// ---------------------------------------------------------------------------
// Kernel 2: per batch row — approx global top-24 merge (static sorted-insert,
// no scratch), fp64 exact recompute, exact sort -> top-16, softmax, gather.
// ---------------------------------------------------------------------------
__global__ __launch_bounds__(256) void merge_kernel(
    const float* __restrict__ cs, const int* __restrict__ ci,
    const float* __restrict__ brep, const float* __restrict__ reps,
    const float* __restrict__ acts,
    float* __restrict__ out, int NLISTS, int N, int BA)
{
    const int r = blockIdx.x;
    const int tid = threadIdx.x;
    __shared__ __align__(16) float xrow[512];
    __shared__ float S1s[256 * KM];
    __shared__ int   S1i[256 * KM];
    __shared__ float S2s[32 * KM];
    __shared__ int   S2i[32 * KM];
    __shared__ double fd[KM];
    __shared__ int    fn[KM];

    if (tid < 128)
        *(float4*)(&xrow[tid * 4]) = *(const float4*)(&brep[(size_t)r * 512 + tid * 4]);

    float ls[KM]; int ln[KM];
    #pragma unroll
    for (int j = 0; j < KM; j++) { ls[j] = INF_F; ln[j] = 0x7fffffff; }

    const int total = NLISTS * 16;
    for (int e = tid; e < total; e += 256) {
        const int blk = e >> 4, j = e & 15;
        const size_t a = (size_t)blk * 1024 + (size_t)r * 16 + j;
        const float s = cs[a]; const int n = ci[a];
        if (lexLess(s, n, ls[KM - 1], ln[KM - 1])) {
            ls[KM - 1] = s; ln[KM - 1] = n;
            #pragma unroll
            for (int u = KM - 1; u > 0; --u)
                if (lexLess(ls[u], ln[u], ls[u - 1], ln[u - 1])) {
                    float tf = ls[u]; ls[u] = ls[u - 1]; ls[u - 1] = tf;
                    int   tn = ln[u]; ln[u] = ln[u - 1]; ln[u - 1] = tn;
                }
        }
    }
    #pragma unroll
    for (int j = 0; j < KM; j++) { S1s[tid * KM + j] = ls[j]; S1i[tid * KM + j] = ln[j]; }
    __syncthreads();

    if (tid < 32) {
        #pragma unroll
        for (int j = 0; j < KM; j++) { ls[j] = INF_F; ln[j] = 0x7fffffff; }
        for (int e = tid * 8 * KM; e < (tid * 8 + 8) * KM; e++) {
            const float s = S1s[e]; const int n = S1i[e];
            if (lexLess(s, n, ls[KM - 1], ln[KM - 1])) {
                ls[KM - 1] = s; ln[KM - 1] = n;
                #pragma unroll
                for (int u = KM - 1; u > 0; --u)
                    if (lexLess(ls[u], ln[u], ls[u - 1], ln[u - 1])) {
                        float tf = ls[u]; ls[u] = ls[u - 1]; ls[u - 1] = tf;
                        int   tn = ln[u]; ln[u] = ln[u - 1]; ln[u - 1] = tn;
                    }
            }
        }
        #pragma unroll
        for (int j = 0; j < KM; j++) { S2s[tid * KM + j] = ls[j]; S2i[tid * KM + j] = ln[j]; }
    }
    __syncthreads();

    if (tid == 0) {
        #pragma unroll
        for (int j = 0; j < KM; j++) { ls[j] = INF_F; ln[j] = 0x7fffffff; }
        for (int e = 0; e < 32 * KM; e++) {
            const float s = S2s[e]; const int n = S2i[e];
            if (lexLess(s, n, ls[KM - 1], ln[KM - 1])) {
                ls[KM - 1] = s; ln[KM - 1] = n;
                #pragma unroll
                for (int u = KM - 1; u > 0; --u)
                    if (lexLess(ls[u], ln[u], ls[u - 1], ln[u - 1])) {
                        float tf = ls[u]; ls[u] = ls[u - 1]; ls[u - 1] = tf;
                        int   tn = ln[u]; ln[u] = ln[u - 1]; ln[u - 1] = tn;
                    }
            }
        }
        for (int j = 0; j < KM; j++) fn[j] = ln[j];
    }
    __syncthreads();

    if (tid < KM) {
        const int n = fn[tid];
        double d = 1.0e300;
        if (n >= 0 && n < N) {
            d = 0.0;
            const float* yp = reps + (size_t)n * 512;
            for (int i = 0; i < 512; i += 4) {
                float4 yv = *(const float4*)(yp + i);
                double d0 = (double)xrow[i + 0] - (double)yv.x;
                double d1 = (double)xrow[i + 1] - (double)yv.y;
                double d2 = (double)xrow[i + 2] - (double)yv.z;
                double d3 = (double)xrow[i + 3] - (double)yv.w;
                d += d0 * d0 + d1 * d1 + d2 * d2 + d3 * d3;
            }
        }
        fd[tid] = d;
    }
    __syncthreads();

    if (tid == 0) {
        int ord[KM];
        for (int j = 0; j < KM; j++) ord[j] = j;
        for (int a = 0; a < 16; a++) {
            int best = a;
            for (int u = a + 1; u < KM; u++) {
                const int ou = ord[u], ob = ord[best];
                if (fd[ou] < fd[ob] || (fd[ou] == fd[ob] && fn[ou] < fn[ob])) best = u;
            }
            int tmp = ord[a]; ord[a] = ord[best]; ord[best] = tmp;
        }
        double dist[16];
        for (int j = 0; j < 16; j++) {
            double v = fd[ord[j]];
            dist[j] = sqrt(v > 0.0 ? v : 0.0);
        }
        double wv[16], wsum = 0.0;
        for (int j = 0; j < 16; j++) { wv[j] = exp(dist[0] - dist[j]); wsum += wv[j]; }
        for (int a = 0; a < 7; a++) {
            double s = 0.0;
            for (int j = 0; j < 16; j++)
                s += wv[j] * (double)acts[(size_t)fn[ord[j]] * 7 + a];
            out[r * 7 + a] = (float)(s / wsum);
        }
        for (int j = 0; j < 16; j++)
            out[BA + r * 16 + j] = (float)fn[ord[j]];
    }
}

extern "C" void kernel_launch(void* const* d_in, const int* in_sizes, int n_in,
                              void* d_out, int out_size, void* d_ws, size_t ws_size,
                              hipStream_t stream) {
    const float* brep = (const float*)d_in[0];
    const float* reps = (const float*)d_in[1];
    const float* acts = (const float*)d_in[2];
    const int D = 512;
    const int B = in_sizes[0] / D;   // 64
    const int N = in_sizes[1] / D;   // 500000
    float* out = (float*)d_out;

    // dist blocks: 1 per CU (141KB LDS). One 64-row top-16 list per block.
    int NBLK = 256;
    const size_t perblk = (size_t)64 * 16 * 8;        // cs+ci bytes per block
    while (NBLK > 1 && (size_t)NBLK * perblk + 65536 > ws_size) NBLK >>= 1;

    float* cs = (float*)d_ws;
    int* ci = (int*)((char*)d_ws + (size_t)NBLK * 64 * 16 * 4);
    uint4* xfrag = (uint4*)((char*)d_ws + (size_t)NBLK * perblk);

    const int TT = (N + 63) / 64;                     // 64-row tiles
    const int tilesBase = TT / NBLK;
    const int tilesRem = TT % NBLK;

    prepack_kernel<<<16, 256, 0, stream>>>(brep, xfrag);
    dist_topk_kernel<<<NBLK, 256, 0, stream>>>(reps, xfrag, cs, ci, N, tilesBase, tilesRem);
    merge_kernel<<<B, 256, 0, stream>>>(cs, ci, brep, reps, acts, out, NBLK, N, B * 7);
}

// Round 9
// 2211.596 us; speedup vs baseline: 1.2770x; 1.2770x over previous
//
#include <hip/hip_runtime.h>
#include <stdint.h>

typedef _Float16 f16;
typedef _Float16 f16x8 __attribute__((ext_vector_type(8)));
typedef float f32x4 __attribute__((ext_vector_type(4)));

#define INF_F __builtin_inff()
#define INF_I 0x7fffffff
#define KM 24            // merge candidate margin
#define SCALE 262144.0f  // 2^18 fixed-point scale

__device__ __forceinline__ bool lexLess(float s1, int n1, float s2, int n2) {
    return (s1 < s2) || (s1 == s2 && n1 < n2);
}
__device__ __forceinline__ bool lexLessI(int s1, int n1, int s2, int n2) {
    return (s1 < s2) || (s1 == s2 && n1 < n2);
}

#define GLOAD_LDS16(gsrc, ldst)                                                  \
    __builtin_amdgcn_global_load_lds(                                            \
        (const __attribute__((address_space(1))) uint32_t*)(gsrc),               \
        (__attribute__((address_space(3))) uint32_t*)(ldst), 16, 0, 0)

// ---------------------------------------------------------------------------
// Kernel 0: pack brep [64,512] f32 -> f16 MFMA A-fragments, coalesced layout:
// xfrag[(ksG*4+ms)*64 + lane] = uint4 of A[m=ms*16+(lane&15)]
// [k = ksG*32 + (lane>>4)*8 + j], j=0..7.
// ---------------------------------------------------------------------------
__global__ __launch_bounds__(256) void prepack_kernel(
    const float* __restrict__ brep, uint4* __restrict__ xfrag)
{
    const int e = blockIdx.x * 256 + threadIdx.x;   // 0..4095
    if (e >= 4096) return;
    const int lane = e & 63;
    const int ms = (e >> 6) & 3;
    const int ks = e >> 8;
    const int m = ms * 16 + (lane & 15);
    const int k = ks * 32 + (lane >> 4) * 8;
    const float* src = brep + m * 512 + k;
    unsigned short hb[8];
    #pragma unroll
    for (int j = 0; j < 8; j++) {
        f16 v = (f16)src[j];
        hb[j] = __builtin_bit_cast(unsigned short, v);
    }
    uint4 o;
    o.x = (unsigned)hb[0] | ((unsigned)hb[1] << 16);
    o.y = (unsigned)hb[2] | ((unsigned)hb[3] << 16);
    o.z = (unsigned)hb[4] | ((unsigned)hb[5] << 16);
    o.w = (unsigned)hb[6] | ((unsigned)hb[7] << 16);
    xfrag[e] = o;
}

// ---------------------------------------------------------------------------
// Kernel 1: k-split streaming scores + per-block top-16 per batch row.
// 4 waves; wave w owns k-quarter [128w, 128w+128) with its A-slice in 64 VGPRs.
// Per tile (64 rep rows): wave processes 16 private 2KB chunks
// (16 rows x 32 floats, each row one 128B cache line, source pre-XOR-swizzled
// so LDS reads are conflict-free), depth-3 gload_lds pipeline, vmcnt(6),
// NO barriers in the chunk loop. Partial dots + ynorm accumulate into a
// double-buffered int32 slds via ds_add (exact, deterministic). One barrier
// per tile; rotating scan wave does top-16 + zeroes the retired buffer while
// the other waves accumulate the next tile.
// ---------------------------------------------------------------------------
__global__ __launch_bounds__(256, 4) void dist_topk_kernel(
    const float* __restrict__ reps, const uint4* __restrict__ xfrag,
    float* __restrict__ cs, int* __restrict__ ci,
    int N, int tilesBase, int tilesRem)
{
    __shared__ __align__(16) char ybuf[4][4][2048];   // [wave][slot][2KB] = 32 KB
    __shared__ int slds[2][64][67];                   // [buf][rep-row][64 dots + ynorm@64]
    __shared__ int topdI[16][64];
    __shared__ int topiI[16][64];
    __shared__ int thrS[64], thrnS[64], cntS[64];

    const int tid = threadIdx.x;
    const int w = tid >> 6, lane = tid & 63;
    const int li = lane & 15, q = lane >> 4;
    const int b = blockIdx.x;
    const int t0 = b * tilesBase + min(b, tilesRem);
    const int tcount = tilesBase + (b < tilesRem ? 1 : 0);
    const int NT = tcount * 16;                       // chunks per wave

    // ---- one-time: A-slice for this wave's k-quarter into registers ----
    uint4 a[4][4];
    #pragma unroll
    for (int ks = 0; ks < 4; ks++)
        #pragma unroll
        for (int mt = 0; mt < 4; mt++)
            a[ks][mt] = xfrag[(((w * 4 + ks) * 4) + mt) * 64 + lane];

    if (tid < 64) { thrS[tid] = INF_I; thrnS[tid] = INF_I; cntS[tid] = 0; }
    for (int i = tid; i < 2 * 64 * 67; i += 256) ((int*)slds)[i] = 0;
    __syncthreads();   // full drain once (also retires the a[] loads)

    // stage chunk c: 16 rows x 32 floats of this wave's k-quarter.
    // LDS slot (row, piece p) <- global piece p^(row&7)  (pieces are 16B).
    const int swsrc = (((lane & 7) ^ (lane >> 3)) << 4);
    auto stage = [&](int c) {
        const int tI = c >> 4, nsub = (c >> 2) & 3, ks = c & 3;
        const long rowb = (long)(t0 + tI) * 64 + nsub * 16;
        const int kf = 128 * w + 32 * ks;             // float offset within row
        char* dst = ybuf[w][c & 3];
        #pragma unroll
        for (int i = 0; i < 2; i++) {
            long r = rowb + i * 8 + (lane >> 3);
            if (r >= N) r = N - 1;
            const char* src = (const char*)(reps + r * 512 + kf) + swsrc;
            GLOAD_LDS16(src, dst + i * 1024);
        }
    };

    stage(0); stage(1); stage(2);

    const int rd0 = li * 128 + (((2 * q + 0) ^ (li & 7)) << 4);
    const int rd1 = li * 128 + (((2 * q + 1) ^ (li & 7)) << 4);

    for (int ti = 0; ti < tcount; ti++) {
        const int n0 = (t0 + ti) * 64;
        int* sb = &slds[ti & 1][0][0];

        #pragma unroll 1
        for (int nsub = 0; nsub < 4; nsub++) {
            f32x4 acc0 = {0.f,0.f,0.f,0.f}, acc1 = {0.f,0.f,0.f,0.f};
            f32x4 acc2 = {0.f,0.f,0.f,0.f}, acc3 = {0.f,0.f,0.f,0.f};
            float ynacc = 0.f;

            #pragma unroll
            for (int ks = 0; ks < 4; ks++) {
                const int cc = (ti * 4 + nsub) * 4 + ks;
                stage(min(cc + 3, NT - 1));
                asm volatile("s_waitcnt vmcnt(6)");
                __builtin_amdgcn_sched_barrier(0);
                const char* yb = ybuf[w][cc & 3];
                const float4 y0 = *(const float4*)(yb + rd0);
                const float4 y1 = *(const float4*)(yb + rd1);
                ynacc = fmaf(y0.x, y0.x, fmaf(y0.y, y0.y, fmaf(y0.z, y0.z, fmaf(y0.w, y0.w, ynacc))));
                ynacc = fmaf(y1.x, y1.x, fmaf(y1.y, y1.y, fmaf(y1.z, y1.z, fmaf(y1.w, y1.w, ynacc))));
                const auto p0 = __builtin_amdgcn_cvt_pkrtz(y0.x, y0.y);
                const auto p1 = __builtin_amdgcn_cvt_pkrtz(y0.z, y0.w);
                const auto p2 = __builtin_amdgcn_cvt_pkrtz(y1.x, y1.y);
                const auto p3 = __builtin_amdgcn_cvt_pkrtz(y1.z, y1.w);
                uint4 bu;
                bu.x = __builtin_bit_cast(unsigned, p0);
                bu.y = __builtin_bit_cast(unsigned, p1);
                bu.z = __builtin_bit_cast(unsigned, p2);
                bu.w = __builtin_bit_cast(unsigned, p3);
                const f16x8 bf = __builtin_bit_cast(f16x8, bu);
                acc0 = __builtin_amdgcn_mfma_f32_16x16x32_f16(__builtin_bit_cast(f16x8, a[ks][0]), bf, acc0, 0, 0, 0);
                acc1 = __builtin_amdgcn_mfma_f32_16x16x32_f16(__builtin_bit_cast(f16x8, a[ks][1]), bf, acc1, 0, 0, 0);
                acc2 = __builtin_amdgcn_mfma_f32_16x16x32_f16(__builtin_bit_cast(f16x8, a[ks][2]), bf, acc2, 0, 0, 0);
                acc3 = __builtin_amdgcn_mfma_f32_16x16x32_f16(__builtin_bit_cast(f16x8, a[ks][3]), bf, acc3, 0, 0, 0);
            }

            // ---- fold this wave's k-quarter partials into slds (exact int) ----
            const int nloc = nsub * 16 + li;          // local rep row 0..63
            float yq2 = ynacc;
            yq2 += __shfl_xor(yq2, 16);
            yq2 += __shfl_xor(yq2, 32);
            if (q == 0)
                atomicAdd(sb + nloc * 67 + 64, __float2int_rn(yq2 * SCALE));
            #pragma unroll
            for (int jj = 0; jj < 4; jj++) {
                atomicAdd(sb + nloc * 67 + ( 0 + 4 * q + jj), __float2int_rn(acc0[jj] * SCALE));
                atomicAdd(sb + nloc * 67 + (16 + 4 * q + jj), __float2int_rn(acc1[jj] * SCALE));
                atomicAdd(sb + nloc * 67 + (32 + 4 * q + jj), __float2int_rn(acc2[jj] * SCALE));
                atomicAdd(sb + nloc * 67 + (48 + 4 * q + jj), __float2int_rn(acc3[jj] * SCALE));
            }
        }

        // ---- tile end: one barrier; rotating wave scans + zeroes buffer ----
        asm volatile("s_waitcnt lgkmcnt(0)" ::: "memory");
        __builtin_amdgcn_sched_barrier(0);
        __builtin_amdgcn_s_barrier();
        asm volatile("" ::: "memory");

        if (w == (ti & 3)) {
            const int r = lane;                       // batch row 0..63
            int thr = thrS[r], thrn = thrnS[r], cnt = cntS[r];
            for (int j = 0; j < 64; j++) {
                const int n = n0 + j;
                if (n >= N) break;
                const int s = sb[j * 67 + 64] - 2 * sb[j * 67 + r];
                if (lexLessI(s, n, thr, thrn)) {
                    if (cnt < 16) {
                        topdI[cnt][r] = s; topiI[cnt][r] = n; cnt++;
                        if (cnt == 16) {
                            int tv = topdI[0][r], tn = topiI[0][r];
                            #pragma unroll
                            for (int u = 1; u < 16; u++) {
                                int v = topdI[u][r], nn = topiI[u][r];
                                if (!lexLessI(v, nn, tv, tn)) { tv = v; tn = nn; }
                            }
                            thr = tv; thrn = tn;
                        }
                    } else {
                        #pragma unroll
                        for (int u = 0; u < 16; u++)
                            if (topdI[u][r] == thr && topiI[u][r] == thrn) {
                                topdI[u][r] = s; topiI[u][r] = n; break;
                            }
                        int tv = topdI[0][r], tn = topiI[0][r];
                        #pragma unroll
                        for (int u = 1; u < 16; u++) {
                            int v = topdI[u][r], nn = topiI[u][r];
                            if (!lexLessI(v, nn, tv, tn)) { tv = v; tn = nn; }
                        }
                        thr = tv; thrn = tn;
                    }
                }
            }
            thrS[r] = thr; thrnS[r] = thrn; cntS[r] = cnt;
            // zero the retired buffer for tile ti+2 (idle until then)
            for (int e2 = lane; e2 < 64 * 67; e2 += 64) sb[e2] = 0;
        }
    }

    __syncthreads();
    if (tid < 64) {
        const int c = cntS[tid];
        const size_t base = ((size_t)b * 64 + tid) * 16;
        for (int j = 0; j < 16; j++) {
            cs[base + j] = (j < c) ? ((float)topdI[j][tid] * (1.0f / SCALE)) : INF_F;
            ci[base + j] = (j < c) ? topiI[j][tid] : INF_I;
        }
    }
}

// ---------------------------------------------------------------------------
// Kernel 2: per batch row — approx global top-24 merge (static sorted-insert),
// fp64 exact recompute, exact sort -> top-16, softmax, gather.
// ---------------------------------------------------------------------------
__global__ __launch_bounds__(256) void merge_kernel(
    const float* __restrict__ cs, const int* __restrict__ ci,
    const float* __restrict__ brep, const float* __restrict__ reps,
    const float* __restrict__ acts,
    float* __restrict__ out, int NLISTS, int N, int BA)
{
    const int r = blockIdx.x;
    const int tid = threadIdx.x;
    __shared__ __align__(16) float xrow[512];
    __shared__ float S1s[256 * KM];
    __shared__ int   S1i[256 * KM];
    __shared__ float S2s[32 * KM];
    __shared__ int   S2i[32 * KM];
    __shared__ double fd[KM];
    __shared__ int    fn[KM];

    if (tid < 128)
        *(float4*)(&xrow[tid * 4]) = *(const float4*)(&brep[(size_t)r * 512 + tid * 4]);

    float ls[KM]; int ln[KM];
    #pragma unroll
    for (int j = 0; j < KM; j++) { ls[j] = INF_F; ln[j] = INF_I; }

    const int total = NLISTS * 16;
    for (int e = tid; e < total; e += 256) {
        const int blk = e >> 4, j = e & 15;
        const size_t a = (size_t)blk * 1024 + (size_t)r * 16 + j;
        const float s = cs[a]; const int n = ci[a];
        if (lexLess(s, n, ls[KM - 1], ln[KM - 1])) {
            ls[KM - 1] = s; ln[KM - 1] = n;
            #pragma unroll
            for (int u = KM - 1; u > 0; --u)
                if (lexLess(ls[u], ln[u], ls[u - 1], ln[u - 1])) {
                    float tf = ls[u]; ls[u] = ls[u - 1]; ls[u - 1] = tf;
                    int   tn = ln[u]; ln[u] = ln[u - 1]; ln[u - 1] = tn;
                }
        }
    }
    #pragma unroll
    for (int j = 0; j < KM; j++) { S1s[tid * KM + j] = ls[j]; S1i[tid * KM + j] = ln[j]; }
    __syncthreads();

    if (tid < 32) {
        #pragma unroll
        for (int j = 0; j < KM; j++) { ls[j] = INF_F; ln[j] = INF_I; }
        for (int e = tid * 8 * KM; e < (tid * 8 + 8) * KM; e++) {
            const float s = S1s[e]; const int n = S1i[e];
            if (lexLess(s, n, ls[KM - 1], ln[KM - 1])) {
                ls[KM - 1] = s; ln[KM - 1] = n;
                #pragma unroll
                for (int u = KM - 1; u > 0; --u)
                    if (lexLess(ls[u], ln[u], ls[u - 1], ln[u - 1])) {
                        float tf = ls[u]; ls[u] = ls[u - 1]; ls[u - 1] = tf;
                        int   tn = ln[u]; ln[u] = ln[u - 1]; ln[u - 1] = tn;
                    }
            }
        }
        #pragma unroll
        for (int j = 0; j < KM; j++) { S2s[tid * KM + j] = ls[j]; S2i[tid * KM + j] = ln[j]; }
    }
    __syncthreads();

    if (tid == 0) {
        #pragma unroll
        for (int j = 0; j < KM; j++) { ls[j] = INF_F; ln[j] = INF_I; }
        for (int e = 0; e < 32 * KM; e++) {
            const float s = S2s[e]; const int n = S2i[e];
            if (lexLess(s, n, ls[KM - 1], ln[KM - 1])) {
                ls[KM - 1] = s; ln[KM - 1] = n;
                #pragma unroll
                for (int u = KM - 1; u > 0; --u)
                    if (lexLess(ls[u], ln[u], ls[u - 1], ln[u - 1])) {
                        float tf = ls[u]; ls[u] = ls[u - 1]; ls[u - 1] = tf;
                        int   tn = ln[u]; ln[u] = ln[u - 1]; ln[u - 1] = tn;
                    }
            }
        }
        for (int j = 0; j < KM; j++) fn[j] = ln[j];
    }
    __syncthreads();

    if (tid < KM) {
        const int n = fn[tid];
        double d = 1.0e300;
        if (n >= 0 && n < N) {
            d = 0.0;
            const float* yp = reps + (size_t)n * 512;
            for (int i = 0; i < 512; i += 4) {
                float4 yv = *(const float4*)(yp + i);
                double d0 = (double)xrow[i + 0] - (double)yv.x;
                double d1 = (double)xrow[i + 1] - (double)yv.y;
                double d2 = (double)xrow[i + 2] - (double)yv.z;
                double d3 = (double)xrow[i + 3] - (double)yv.w;
                d += d0 * d0 + d1 * d1 + d2 * d2 + d3 * d3;
            }
        }
        fd[tid] = d;
    }
    __syncthreads();

    if (tid == 0) {
        int ord[KM];
        for (int j = 0; j < KM; j++) ord[j] = j;
        for (int a = 0; a < 16; a++) {
            int best = a;
            for (int u = a + 1; u < KM; u++) {
                const int ou = ord[u], ob = ord[best];
                if (fd[ou] < fd[ob] || (fd[ou] == fd[ob] && fn[ou] < fn[ob])) best = u;
            }
            int tmp = ord[a]; ord[a] = ord[best]; ord[best] = tmp;
        }
        double dist[16];
        for (int j = 0; j < 16; j++) {
            double v = fd[ord[j]];
            dist[j] = sqrt(v > 0.0 ? v : 0.0);
        }
        double wv[16], wsum = 0.0;
        for (int j = 0; j < 16; j++) { wv[j] = exp(dist[0] - dist[j]); wsum += wv[j]; }
        for (int a = 0; a < 7; a++) {
            double s = 0.0;
            for (int j = 0; j < 16; j++)
                s += wv[j] * (double)acts[(size_t)fn[ord[j]] * 7 + a];
            out[r * 7 + a] = (float)(s / wsum);
        }
        for (int j = 0; j < 16; j++)
            out[BA + r * 16 + j] = (float)fn[ord[j]];
    }
}

extern "C" void kernel_launch(void* const* d_in, const int* in_sizes, int n_in,
                              void* d_out, int out_size, void* d_ws, size_t ws_size,
                              hipStream_t stream) {
    const float* brep = (const float*)d_in[0];
    const float* reps = (const float*)d_in[1];
    const float* acts = (const float*)d_in[2];
    const int D = 512;
    const int B = in_sizes[0] / D;   // 64
    const int N = in_sizes[1] / D;   // 500000
    float* out = (float*)d_out;

    // 512 blocks = 2/CU (76KB LDS each). One 64-row top-16 list per block.
    int NBLK = 512;
    const size_t perblk = (size_t)64 * 16 * 8;        // cs+ci bytes per block
    while (NBLK > 1 && (size_t)NBLK * perblk + 65536 > ws_size) NBLK >>= 1;

    float* cs = (float*)d_ws;
    int* ci = (int*)((char*)d_ws + (size_t)NBLK * 64 * 16 * 4);
    uint4* xfrag = (uint4*)((char*)d_ws + (size_t)NBLK * perblk);

    const int TT = (N + 63) / 64;                     // 64-row tiles
    const int tilesBase = TT / NBLK;
    const int tilesRem = TT % NBLK;

    prepack_kernel<<<16, 256, 0, stream>>>(brep, xfrag);
    dist_topk_kernel<<<NBLK, 256, 0, stream>>>(reps, xfrag, cs, ci, N, tilesBase, tilesRem);
    merge_kernel<<<B, 256, 0, stream>>>(cs, ci, brep, reps, acts, out, NBLK, N, B * 7);
}

// Round 10
// 1248.994 us; speedup vs baseline: 2.2612x; 1.7707x over previous
//
#include <hip/hip_runtime.h>
#include <stdint.h>

typedef _Float16 f16;
typedef _Float16 f16x8 __attribute__((ext_vector_type(8)));
typedef float f32x4 __attribute__((ext_vector_type(4)));

#define INF_F __builtin_inff()
#define INF_I 0x7fffffff
#define KM 24            // merge candidate margin
#define SCALE 262144.0f  // 2^18 fixed-point scale

__device__ __forceinline__ bool lexLess(float s1, int n1, float s2, int n2) {
    return (s1 < s2) || (s1 == s2 && n1 < n2);
}
__device__ __forceinline__ bool lexLessI(int s1, int n1, int s2, int n2) {
    return (s1 < s2) || (s1 == s2 && n1 < n2);
}

__device__ __forceinline__ uint4 pack8(const float4 a, const float4 b) {
    const auto p0 = __builtin_amdgcn_cvt_pkrtz(a.x, a.y);
    const auto p1 = __builtin_amdgcn_cvt_pkrtz(a.z, a.w);
    const auto p2 = __builtin_amdgcn_cvt_pkrtz(b.x, b.y);
    const auto p3 = __builtin_amdgcn_cvt_pkrtz(b.z, b.w);
    uint4 u;
    u.x = __builtin_bit_cast(unsigned, p0);
    u.y = __builtin_bit_cast(unsigned, p1);
    u.z = __builtin_bit_cast(unsigned, p2);
    u.w = __builtin_bit_cast(unsigned, p3);
    return u;
}

// ---------------------------------------------------------------------------
// Kernel 1: k-split streaming scores + per-block top-16 per batch row.
// 4 waves; wave w owns k-quarter [128w, 128w+128). Its A-slice (all 64 batch
// rows x 128 k) lives in 64 VGPRs, built in-kernel from brep (L2-hot) — the
// k-loop issues ONLY the y-stream to VMEM, direct global->VGPR (the proven
// fast path: R6 hit 2.3 TB/s raw; every global_load_lds variant <0.9).
// Per tile (64 rep rows): 4 nsub x 4 ks, depth-1 y prefetch, 16 MFMAs;
// partial dots + ynorm fold into int32 slds via ds_atomic (exact,
// deterministic). 2 barriers/tile; rotating wave scans top-16 and re-zeroes.
// Tiles assigned strided (t = b + s*NBLK) for perfect balance.
// ---------------------------------------------------------------------------
__global__ __launch_bounds__(256, 4) void dist_topk_kernel(
    const float* __restrict__ reps, const float* __restrict__ brep,
    float* __restrict__ cs, int* __restrict__ ci,
    int N, int TT, int NBLK)
{
    __shared__ int slds[64][65];                  // [rep-row][64 dots + ynorm]
    __shared__ int topdI[16][64];
    __shared__ int topiI[16][64];
    __shared__ int thrS[64], thrnS[64], cntS[64];

    const int tid = threadIdx.x;
    const int w = tid >> 6, lane = tid & 63;
    const int li = lane & 15, q = lane >> 4;
    const int b = blockIdx.x;

    // ---- A-fragments for this wave's k-quarter, in registers (64 VGPR) ----
    // a[ks][mt] holds A[m = mt*16 + li][k = 128w + 32ks + 8q + j], j=0..7
    uint4 a[4][4];
    #pragma unroll
    for (int ks = 0; ks < 4; ks++)
        #pragma unroll
        for (int mt = 0; mt < 4; mt++) {
            const float* src = brep + (mt * 16 + li) * 512 + 128 * w + 32 * ks + 8 * q;
            const float4 x0 = *(const float4*)(src);
            const float4 x1 = *(const float4*)(src + 4);
            a[ks][mt] = pack8(x0, x1);
        }

    if (tid < 64) { thrS[tid] = INF_I; thrnS[tid] = INF_I; cntS[tid] = 0; }
    for (int i = tid; i < 64 * 65; i += 256) ((int*)slds)[i] = 0;
    __syncthreads();

    int sc = 0;
    for (int t = b; t < TT; t += NBLK, sc++) {
        const int n0 = t * 64;

        #pragma unroll 1
        for (int nsub = 0; nsub < 4; nsub++) {
            const int rowl = n0 + nsub * 16 + li;
            const size_t rowc = (size_t)(rowl < N ? rowl : N - 1);
            const float* bp = reps + rowc * 512 + 128 * w + 8 * q;

            f32x4 acc0 = {0.f,0.f,0.f,0.f}, acc1 = {0.f,0.f,0.f,0.f};
            f32x4 acc2 = {0.f,0.f,0.f,0.f}, acc3 = {0.f,0.f,0.f,0.f};
            float yn = 0.f;

            float4 y0A = *(const float4*)(bp);
            float4 y1A = *(const float4*)(bp + 4);
            #pragma unroll
            for (int ks = 0; ks < 4; ks++) {
                float4 y0B, y1B;
                if (ks < 3) {
                    y0B = *(const float4*)(bp + (ks + 1) * 32);
                    y1B = *(const float4*)(bp + (ks + 1) * 32 + 4);
                }
                yn = fmaf(y0A.x, y0A.x, fmaf(y0A.y, y0A.y, fmaf(y0A.z, y0A.z, fmaf(y0A.w, y0A.w, yn))));
                yn = fmaf(y1A.x, y1A.x, fmaf(y1A.y, y1A.y, fmaf(y1A.z, y1A.z, fmaf(y1A.w, y1A.w, yn))));
                const f16x8 bf = __builtin_bit_cast(f16x8, pack8(y0A, y1A));
                acc0 = __builtin_amdgcn_mfma_f32_16x16x32_f16(__builtin_bit_cast(f16x8, a[ks][0]), bf, acc0, 0, 0, 0);
                acc1 = __builtin_amdgcn_mfma_f32_16x16x32_f16(__builtin_bit_cast(f16x8, a[ks][1]), bf, acc1, 0, 0, 0);
                acc2 = __builtin_amdgcn_mfma_f32_16x16x32_f16(__builtin_bit_cast(f16x8, a[ks][2]), bf, acc2, 0, 0, 0);
                acc3 = __builtin_amdgcn_mfma_f32_16x16x32_f16(__builtin_bit_cast(f16x8, a[ks][3]), bf, acc3, 0, 0, 0);
                if (ks < 3) { y0A = y0B; y1A = y1B; }
            }

            // fold this wave's k-quarter partials into slds (exact int32)
            float ys = yn;
            ys += __shfl_xor(ys, 16);
            ys += __shfl_xor(ys, 32);
            const int nloc = nsub * 16 + li;
            if (q == 0) atomicAdd(&slds[nloc][64], __float2int_rn(ys * SCALE));
            #pragma unroll
            for (int jj = 0; jj < 4; jj++) {
                atomicAdd(&slds[nloc][ 0 + 4 * q + jj], __float2int_rn(acc0[jj] * SCALE));
                atomicAdd(&slds[nloc][16 + 4 * q + jj], __float2int_rn(acc1[jj] * SCALE));
                atomicAdd(&slds[nloc][32 + 4 * q + jj], __float2int_rn(acc2[jj] * SCALE));
                atomicAdd(&slds[nloc][48 + 4 * q + jj], __float2int_rn(acc3[jj] * SCALE));
            }
        }

        __syncthreads();   // all atomics of this tile done

        if (w == (sc & 3)) {
            const int r = lane;                   // batch row 0..63
            const int* sb = &slds[0][0];
            int thr = thrS[r], thrn = thrnS[r], cnt = cntS[r];
            for (int j = 0; j < 64; j++) {
                const int n = n0 + j;
                if (n >= N) break;
                const int s = sb[j * 65 + 64] - 2 * sb[j * 65 + r];
                if (lexLessI(s, n, thr, thrn)) {
                    if (cnt < 16) {
                        topdI[cnt][r] = s; topiI[cnt][r] = n; cnt++;
                        if (cnt == 16) {
                            int tv = topdI[0][r], tn = topiI[0][r];
                            #pragma unroll
                            for (int u = 1; u < 16; u++) {
                                int v = topdI[u][r], nn = topiI[u][r];
                                if (!lexLessI(v, nn, tv, tn)) { tv = v; tn = nn; }
                            }
                            thr = tv; thrn = tn;
                        }
                    } else {
                        #pragma unroll
                        for (int u = 0; u < 16; u++)
                            if (topdI[u][r] == thr && topiI[u][r] == thrn) {
                                topdI[u][r] = s; topiI[u][r] = n; break;
                            }
                        int tv = topdI[0][r], tn = topiI[0][r];
                        #pragma unroll
                        for (int u = 1; u < 16; u++) {
                            int v = topdI[u][r], nn = topiI[u][r];
                            if (!lexLessI(v, nn, tv, tn)) { tv = v; tn = nn; }
                        }
                        thr = tv; thrn = tn;
                    }
                }
            }
            thrS[r] = thr; thrnS[r] = thrn; cntS[r] = cnt;
            // zero slds for the next tile (scan wave owns this window)
            for (int e2 = lane; e2 < 64 * 65; e2 += 64) (&slds[0][0])[e2] = 0;
        }

        __syncthreads();   // slds zeroed before next tile's atomics
    }

    __syncthreads();
    if (tid < 64) {
        const int c = cntS[tid];
        const size_t base = ((size_t)b * 64 + tid) * 16;
        for (int j = 0; j < 16; j++) {
            cs[base + j] = (j < c) ? ((float)topdI[j][tid] * (1.0f / SCALE)) : INF_F;
            ci[base + j] = (j < c) ? topiI[j][tid] : INF_I;
        }
    }
}

// ---------------------------------------------------------------------------
// Kernel 2: per batch row — approx global top-24 merge (replace-max, the
// R2-R6-proven fast variant), fp64 exact recompute, exact sort -> top-16,
// softmax weights, action gather, outputs.
// ---------------------------------------------------------------------------
__global__ __launch_bounds__(256) void merge_kernel(
    const float* __restrict__ cs, const int* __restrict__ ci,
    const float* __restrict__ brep, const float* __restrict__ reps,
    const float* __restrict__ acts,
    float* __restrict__ out, int NLISTS, int N, int BA)
{
    const int r = blockIdx.x;
    const int tid = threadIdx.x;
    __shared__ __align__(16) float xrow[512];
    __shared__ float S1s[256 * KM];
    __shared__ int   S1i[256 * KM];
    __shared__ float S2s[32 * KM];
    __shared__ int   S2i[32 * KM];
    __shared__ double fd[KM];
    __shared__ int    fn[KM];

    if (tid < 128)
        *(float4*)(&xrow[tid * 4]) = *(const float4*)(&brep[(size_t)r * 512 + tid * 4]);

    float ls[KM]; int li[KM];
    #pragma unroll
    for (int j = 0; j < KM; j++) { ls[j] = INF_F; li[j] = INF_I; }
    float mv = INF_F; int mn = INF_I; int mp = 0;
    const int total = NLISTS * 16;
    for (int e = tid; e < total; e += 256) {
        const int blk = e >> 4, j = e & 15;
        const size_t a = (size_t)blk * 1024 + (size_t)r * 16 + j;
        const float s = cs[a]; const int n = ci[a];
        if (lexLess(s, n, mv, mn)) {
            ls[mp] = s; li[mp] = n;
            mv = ls[0]; mn = li[0]; mp = 0;
            #pragma unroll
            for (int u = 1; u < KM; u++)
                if (!lexLess(ls[u], li[u], mv, mn)) { mv = ls[u]; mn = li[u]; mp = u; }
        }
    }
    #pragma unroll
    for (int j = 0; j < KM; j++) { S1s[tid * KM + j] = ls[j]; S1i[tid * KM + j] = li[j]; }
    __syncthreads();

    if (tid < 32) {
        #pragma unroll
        for (int j = 0; j < KM; j++) { ls[j] = INF_F; li[j] = INF_I; }
        mv = INF_F; mn = INF_I; mp = 0;
        for (int e = tid * 8 * KM; e < (tid * 8 + 8) * KM; e++) {
            const float s = S1s[e]; const int n = S1i[e];
            if (lexLess(s, n, mv, mn)) {
                ls[mp] = s; li[mp] = n;
                mv = ls[0]; mn = li[0]; mp = 0;
                #pragma unroll
                for (int u = 1; u < KM; u++)
                    if (!lexLess(ls[u], li[u], mv, mn)) { mv = ls[u]; mn = li[u]; mp = u; }
            }
        }
        #pragma unroll
        for (int j = 0; j < KM; j++) { S2s[tid * KM + j] = ls[j]; S2i[tid * KM + j] = li[j]; }
    }
    __syncthreads();

    if (tid == 0) {
        #pragma unroll
        for (int j = 0; j < KM; j++) { ls[j] = INF_F; li[j] = INF_I; }
        mv = INF_F; mn = INF_I; mp = 0;
        for (int e = 0; e < 32 * KM; e++) {
            const float s = S2s[e]; const int n = S2i[e];
            if (lexLess(s, n, mv, mn)) {
                ls[mp] = s; li[mp] = n;
                mv = ls[0]; mn = li[0]; mp = 0;
                #pragma unroll
                for (int u = 1; u < KM; u++)
                    if (!lexLess(ls[u], li[u], mv, mn)) { mv = ls[u]; mn = li[u]; mp = u; }
            }
        }
        for (int j = 0; j < KM; j++) fn[j] = li[j];
    }
    __syncthreads();

    if (tid < KM) {
        const int n = fn[tid];
        double d = 1.0e300;
        if (n >= 0 && n < N) {
            d = 0.0;
            const float* yp = reps + (size_t)n * 512;
            for (int i = 0; i < 512; i += 4) {
                float4 yv = *(const float4*)(yp + i);
                double d0 = (double)xrow[i + 0] - (double)yv.x;
                double d1 = (double)xrow[i + 1] - (double)yv.y;
                double d2 = (double)xrow[i + 2] - (double)yv.z;
                double d3 = (double)xrow[i + 3] - (double)yv.w;
                d += d0 * d0 + d1 * d1 + d2 * d2 + d3 * d3;
            }
        }
        fd[tid] = d;
    }
    __syncthreads();

    if (tid == 0) {
        int ord[KM];
        for (int j = 0; j < KM; j++) ord[j] = j;
        for (int a = 0; a < 16; a++) {
            int best = a;
            for (int u = a + 1; u < KM; u++) {
                const int ou = ord[u], ob = ord[best];
                if (fd[ou] < fd[ob] || (fd[ou] == fd[ob] && fn[ou] < fn[ob])) best = u;
            }
            int tmp = ord[a]; ord[a] = ord[best]; ord[best] = tmp;
        }
        double dist[16];
        for (int j = 0; j < 16; j++) {
            double v = fd[ord[j]];
            dist[j] = sqrt(v > 0.0 ? v : 0.0);
        }
        double wv[16], wsum = 0.0;
        for (int j = 0; j < 16; j++) { wv[j] = exp(dist[0] - dist[j]); wsum += wv[j]; }
        for (int a = 0; a < 7; a++) {
            double s = 0.0;
            for (int j = 0; j < 16; j++)
                s += wv[j] * (double)acts[(size_t)fn[ord[j]] * 7 + a];
            out[r * 7 + a] = (float)(s / wsum);
        }
        for (int j = 0; j < 16; j++)
            out[BA + r * 16 + j] = (float)fn[ord[j]];
    }
}

extern "C" void kernel_launch(void* const* d_in, const int* in_sizes, int n_in,
                              void* d_out, int out_size, void* d_ws, size_t ws_size,
                              hipStream_t stream) {
    const float* brep = (const float*)d_in[0];
    const float* reps = (const float*)d_in[1];
    const float* acts = (const float*)d_in[2];
    const int D = 512;
    const int B = in_sizes[0] / D;   // 64
    const int N = in_sizes[1] / D;   // 500000
    float* out = (float*)d_out;

    // 1024 blocks = 4/CU (26 KB LDS, <=128 VGPR -> 16 waves/CU).
    int NBLK = 1024;
    const size_t perblk = (size_t)64 * 16 * 8;        // cs+ci bytes per block
    while (NBLK > 1 && (size_t)NBLK * perblk > ws_size) NBLK >>= 1;

    float* cs = (float*)d_ws;
    int* ci = (int*)((char*)d_ws + (size_t)NBLK * 64 * 16 * 4);

    const int TT = (N + 63) / 64;                     // 64-row tiles

    dist_topk_kernel<<<NBLK, 256, 0, stream>>>(reps, brep, cs, ci, N, TT, NBLK);
    merge_kernel<<<B, 256, 0, stream>>>(cs, ci, brep, reps, acts, out, NBLK, N, B * 7);
}